// Round 18
// baseline (400.112 us; speedup 1.0000x reference)
//
#include <hip/hip_runtime.h>
#include <math.h>

#define LRELU_SLOPE 0.2f
#define L2E 1.4426950408889634f

typedef __attribute__((ext_vector_type(8))) short bf16x8;
typedef __attribute__((ext_vector_type(4))) float f32x4;
typedef __attribute__((ext_vector_type(2))) float f2;

__device__ __forceinline__ float fast_exp2(float x) {
  float r; asm("v_exp_f32 %0, %1" : "=v"(r) : "v"(x)); return r;
}

// DPP butterfly add (VALU pipe).
template<int CTRL>
__device__ __forceinline__ float dpp_add(float v) {
  int p = __builtin_amdgcn_update_dpp(0, __float_as_int(v), CTRL, 0xF, 0xF, true);
  return v + __int_as_float(p);
}
__device__ __forceinline__ float row16_sum(float v) {
  v = dpp_add<0xB1>(v);
  v = dpp_add<0x4E>(v);
  v = dpp_add<0x124>(v);
  v = dpp_add<0x128>(v);
  return v;
}

// ---------------- f32 <-> bf16 helpers ----------------
__device__ __forceinline__ unsigned short f2bf(float f) {
  unsigned u = __float_as_uint(f);
  return (unsigned short)((u + 0x7FFFu + ((u >> 16) & 1u)) >> 16);
}
__device__ __forceinline__ f2 bfpair(unsigned p) {
  f2 r;
  r.x = __uint_as_float(p << 16);
  r.y = __uint_as_float(p & 0xffff0000u);
  return r;
}

// all six weight mats W[K][N] f32 -> Wt[N][K] bf16 in one dispatch
__global__ void wt_cvt_all(
    const float* __restrict__ W1l, const float* __restrict__ W1r,
    const float* __restrict__ W2l, const float* __restrict__ W2r,
    const float* __restrict__ W3l, const float* __restrict__ W3r,
    unsigned short* __restrict__ Wt1l, unsigned short* __restrict__ Wt1r,
    unsigned short* __restrict__ Wt2l, unsigned short* __restrict__ Wt2r,
    unsigned short* __restrict__ Wt3l, unsigned short* __restrict__ Wt3r) {
  const float* W; unsigned short* Wt; int K, N;
  switch (blockIdx.y) {
    case 0: W = W1l; Wt = Wt1l; K = 128; N = 256; break;
    case 1: W = W1r; Wt = Wt1r; K = 128; N = 256; break;
    case 2: W = W2l; Wt = Wt2l; K = 256; N = 256; break;
    case 3: W = W2r; Wt = Wt2r; K = 256; N = 256; break;
    case 4: W = W3l; Wt = Wt3l; K = 256; N = 64;  break;
    default: W = W3r; Wt = Wt3r; K = 256; N = 64; break;
  }
  int i = blockIdx.x * blockDim.x + threadIdx.x;
  int k8s = K / 8;
  int n = i / k8s, k8 = i - n * k8s;
  if (n >= N) return;
  unsigned short tmp[8];
#pragma unroll
  for (int j = 0; j < 8; ++j) tmp[j] = f2bf(W[(size_t)(k8 * 8 + j) * N + n]);
  *(bf16x8*)(Wt + (size_t)n * K + k8 * 8) = *(bf16x8*)tmp;
}

// ---------------- dual-side MFMA GEMM, A in LDS, coalesced Y epilogue ----------------
template<int K, bool CVT>
__global__ __launch_bounds__(512) void gemm_dual(
    const void* __restrict__ Xsrc,
    const unsigned short* __restrict__ Wt0, const unsigned short* __restrict__ Wt1,
    const float* __restrict__ bias0, const float* __restrict__ bias1,
    unsigned short* __restrict__ Y0, unsigned short* __restrict__ Y1, int M) {
  constexpr int LDK = K + 8;
  constexpr int SMEM = (64 * LDK > 64 * 256) ? 64 * LDK : 64 * 256;
  __shared__ unsigned short smem[SMEM];
  unsigned short* As = smem;
  const int t = threadIdx.x, w = t >> 6, l = t & 63;
  const int lr = l & 15, lk = l >> 4;
  const int rowBase = blockIdx.x * 64;

  if constexpr (CVT) {
    const float* Xf = (const float*)Xsrc;
    constexpr int SPR = K / 4;
    constexpr int ITER = (64 * SPR) / 512;
#pragma unroll
    for (int i = 0; i < ITER; ++i) {
      int idx = i * 512 + t;
      int row = idx / SPR, seg = idx - row * SPR;
      int gr = rowBase + row; if (gr >= M) gr = M - 1;
      float4 v = *(const float4*)(Xf + (size_t)gr * K + seg * 4);
      ushort4 o;
      o.x = f2bf(v.x); o.y = f2bf(v.y); o.z = f2bf(v.z); o.w = f2bf(v.w);
      *(ushort4*)(As + row * LDK + seg * 4) = o;
    }
  } else {
    const unsigned short* Xb = (const unsigned short*)Xsrc;
    constexpr int SPR = K / 8;
    constexpr int ITER = (64 * SPR) / 512;
#pragma unroll
    for (int i = 0; i < ITER; ++i) {
      int idx = i * 512 + t;
      int row = idx / SPR, seg = idx - row * SPR;
      int gr = rowBase + row; if (gr >= M) gr = M - 1;
      *(uint4*)(As + row * LDK + seg * 8) = *(const uint4*)(Xb + (size_t)gr * K + seg * 8);
    }
  }
  __syncthreads();

  const int side = w >> 2;
  const int n0 = (w & 3) * 64;
  const unsigned short* Wt = side ? Wt1 : Wt0;
  const float* bias = side ? bias1 : bias0;

  f32x4 acc[4][4];
#pragma unroll
  for (int rt = 0; rt < 4; ++rt)
#pragma unroll
    for (int nt = 0; nt < 4; ++nt) acc[rt][nt] = (f32x4){0.f, 0.f, 0.f, 0.f};

  const unsigned short* bp = Wt + (size_t)(n0 + lr) * K + lk * 8;
  const unsigned short* ap = As + lr * LDK + lk * 8;

#pragma unroll
  for (int k0 = 0; k0 < K; k0 += 32) {
    bf16x8 a[4], b[4];
#pragma unroll
    for (int rt = 0; rt < 4; ++rt) a[rt] = *(const bf16x8*)(ap + rt * 16 * LDK + k0);
#pragma unroll
    for (int nt = 0; nt < 4; ++nt) b[nt] = *(const bf16x8*)(bp + nt * 16 * K + k0);
#pragma unroll
    for (int rt = 0; rt < 4; ++rt)
#pragma unroll
      for (int nt = 0; nt < 4; ++nt)
        acc[rt][nt] = __builtin_amdgcn_mfma_f32_16x16x32_bf16(a[rt], b[nt], acc[rt][nt], 0, 0, 0);
  }

  // ---- epilogue: per side, acc -> LDS (bf16) -> full-line stores ----
  unsigned short* ybuf = smem;
#pragma unroll
  for (int sd = 0; sd < 2; ++sd) {
    __syncthreads();
    if (side == sd) {
#pragma unroll
      for (int nt = 0; nt < 4; ++nt) {
        float bv = bias[n0 + nt * 16 + lr];
#pragma unroll
        for (int rt = 0; rt < 4; ++rt)
#pragma unroll
          for (int r = 0; r < 4; ++r)
            ybuf[(rt * 16 + lk * 4 + r) * 256 + n0 + nt * 16 + lr] =
                f2bf(acc[rt][nt][r] + bv);
      }
    }
    __syncthreads();
    unsigned short* Y = sd ? Y1 : Y0;
#pragma unroll
    for (int i = 0; i < 4; ++i) {
      int boff = (i * 512 + t) * 16;
      int row = boff >> 9;
      int col = boff & 511;
      int rg = rowBase + row;
      if (rg < M)
        *(uint4*)((char*)Y + (((size_t)rg << 9) + col)) =
            *(const uint4*)((const char*)ybuf + boff);
    }
  }
}

// ---------------- layer-3 GEMM (N=64 per side), coalesced epilogue ----------------
template<int K>
__global__ __launch_bounds__(256) void gemm_n64(
    const unsigned short* __restrict__ Xb,
    const unsigned short* __restrict__ Wt0, const unsigned short* __restrict__ Wt1,
    const float* __restrict__ bias0, const float* __restrict__ bias1,
    unsigned short* __restrict__ Y0, unsigned short* __restrict__ Y1, int M) {
  __shared__ unsigned short ybuf[64 * 64];
  const int side = blockIdx.y;
  const unsigned short* Wt = side ? Wt1 : Wt0;
  const float* bias = side ? bias1 : bias0;
  unsigned short* Y = side ? Y1 : Y0;
  const int t = threadIdx.x, w = t >> 6, l = t & 63;
  const int lr = l & 15, lk = l >> 4;
  const int rowBase = blockIdx.x * 64 + w * 16;

  f32x4 acc[4];
#pragma unroll
  for (int nt = 0; nt < 4; ++nt) acc[nt] = (f32x4){0.f, 0.f, 0.f, 0.f};

  int arow = rowBase + lr; if (arow >= M) arow = M - 1;
  const unsigned short* ap = Xb + (size_t)arow * K + lk * 8;
  const unsigned short* bp = Wt + (size_t)lr * K + lk * 8;

#pragma unroll
  for (int k0 = 0; k0 < K; k0 += 32) {
    bf16x8 a = *(const bf16x8*)(ap + k0);
    bf16x8 b[4];
#pragma unroll
    for (int nt = 0; nt < 4; ++nt) b[nt] = *(const bf16x8*)(bp + nt * 16 * K + k0);
#pragma unroll
    for (int nt = 0; nt < 4; ++nt)
      acc[nt] = __builtin_amdgcn_mfma_f32_16x16x32_bf16(a, b[nt], acc[nt], 0, 0, 0);
  }

#pragma unroll
  for (int nt = 0; nt < 4; ++nt) {
    float bv = bias[nt * 16 + lr];
#pragma unroll
    for (int r = 0; r < 4; ++r)
      ybuf[(w * 16 + lk * 4 + r) * 64 + nt * 16 + lr] = f2bf(acc[nt][r] + bv);
  }
  __syncthreads();

  const size_t base = (size_t)blockIdx.x * 64 * 64;   // ushort offset of block tile
#pragma unroll
  for (int i = 0; i < 2; ++i) {
    int idx = i * 256 + t;
    int off = idx * 8;                 // ushort offset (16 B)
    int row = off >> 6;                // 64 ushorts per row
    if (blockIdx.x * 64 + row < M)
      *(uint4*)(Y + base + off) = *(const uint4*)(ybuf + off);
  }
}

// ---------------- CSR build ----------------
__global__ void hist_deg(const int* __restrict__ dst, int* __restrict__ deg, int Ee) {
  int e = blockIdx.x * blockDim.x + threadIdx.x;
  if (e < Ee) atomicAdd(&deg[dst[e]], 1);
}

__global__ void scan_blk(const int* __restrict__ deg, int* __restrict__ rowptr,
                         int* __restrict__ bsum, int n) {
  __shared__ int sm[256];
  const int b = blockIdx.x, t = threadIdx.x;
  const int i = b * 256 + t;
  const int v = (i < n) ? deg[i] : 0;
  sm[t] = v;
  __syncthreads();
#pragma unroll
  for (int off = 1; off < 256; off <<= 1) {
    int x = (t >= off) ? sm[t - off] : 0;
    __syncthreads();
    sm[t] += x;
    __syncthreads();
  }
  if (i < n) rowptr[i] = sm[t] - v;
  if (t == 255) bsum[b] = sm[255];
}

__global__ void scan_top(const int* __restrict__ bsum, int* __restrict__ boff,
                         int* __restrict__ rowptr, int nb, int n) {
  __shared__ int sm[1024];
  const int t = threadIdx.x;
  const int v = (t < nb) ? bsum[t] : 0;
  sm[t] = v;
  __syncthreads();
#pragma unroll
  for (int off = 1; off < 1024; off <<= 1) {
    int x = (t >= off) ? sm[t - off] : 0;
    __syncthreads();
    sm[t] += x;
    __syncthreads();
  }
  if (t < nb) boff[t] = sm[t] - v;
  if (t == 1023) rowptr[n] = sm[1023];
}

__global__ void scan_add(int* __restrict__ rowptr, const int* __restrict__ boff, int n) {
  int i = blockIdx.x * 256 + threadIdx.x;
  if (i < n) rowptr[i] += boff[blockIdx.x];
}

// fill via countdown on deg; pads csr_src[Ee .. Ee+15] with 0 (safe gather target)
__global__ void fill_csr(const int* __restrict__ src, const int* __restrict__ dst,
                         const int* __restrict__ rowptr, int* __restrict__ deg,
                         int* __restrict__ csr_src, int Ee) {
  int e = blockIdx.x * blockDim.x + threadIdx.x;
  if (e < Ee) {
    int d = dst[e];
    int p = atomicSub(&deg[d], 1) - 1;
    csr_src[rowptr[d] + p] = src[e];
  } else if (e < Ee + 16) {
    csr_src[e] = 0;
  }
}

// ---------------- fused GATv2 aggregation + bias + LayerNorm (H=4, bf16 out) ----------------
// ONE WAVE PER NODE: lane = 4 contiguous channels. 8 edges per iteration as two
// alternating 4-edge groups (8 gathers in flight, no clamps: csr_src padded,
// OOB edges masked by -INF score).
__global__ __launch_bounds__(256) void gat_fused4(
    const unsigned short* __restrict__ xlb, const unsigned short* __restrict__ xrb,
    const float* __restrict__ att,
    const int* __restrict__ rowptr, const int* __restrict__ csr_src,
    const float* __restrict__ bo, const float* __restrict__ gam,
    const float* __restrict__ bet, unsigned short* __restrict__ outp, int n) {
  const int t = threadIdx.x;
  const int wv = t >> 6, lane = t & 63;
  const int node = blockIdx.x * 4 + wv;
  if (node >= n) return;
  const int cb = lane * 4;
  const unsigned loff = (unsigned)lane << 3;
  const char* xl8 = (const char*)xlb;

  uint2 xp = *(const uint2*)((const char*)xrb + (((unsigned)node << 9) + loff));
  const f2 xr0 = bfpair(xp.x), xr1 = bfpair(xp.y);
  const float4 a4 = *(const float4*)(att + cb);
  const f2 at0 = {a4.x * L2E, a4.y * L2E};
  const f2 at1 = {a4.z * L2E, a4.w * L2E};

  const int r0 = rowptr[node], r1 = rowptr[node + 1];
  float s = 0.f;
  f2 o0 = {0.f, 0.f}, o1 = {0.f, 0.f};

  if (r0 < r1) {
#define GOFF(idx) ((((unsigned)csr_src[idx]) << 9) + loff)
    uint2 A0 = *(const uint2*)(xl8 + GOFF(r0));
    uint2 A1 = *(const uint2*)(xl8 + GOFF(r0 + 1));
    uint2 A2 = *(const uint2*)(xl8 + GOFF(r0 + 2));
    uint2 A3 = *(const uint2*)(xl8 + GOFF(r0 + 3));
    uint2 B0 = *(const uint2*)(xl8 + GOFF(r0 + 4));
    uint2 B1 = *(const uint2*)(xl8 + GOFF(r0 + 5));
    uint2 B2 = *(const uint2*)(xl8 + GOFF(r0 + 6));
    uint2 B3 = *(const uint2*)(xl8 + GOFF(r0 + 7));
    for (int i = r0; i < r1; i += 8) {
      // ---- group A: edges i .. i+3 (i < r1 guaranteed) ----
      {
        const f2 v00 = bfpair(A0.x), v01 = bfpair(A0.y);
        const f2 v10 = bfpair(A1.x), v11 = bfpair(A1.y);
        const f2 v20 = bfpair(A2.x), v21 = bfpair(A2.y);
        const f2 v30 = bfpair(A3.x), v31 = bfpair(A3.y);
        f2 e, q0, q1, q2, q3;
        e = v00 + xr0; e = __builtin_elementwise_max(e, e * LRELU_SLOPE); q0 = e * at0;
        e = v01 + xr1; e = __builtin_elementwise_max(e, e * LRELU_SLOPE); q0 += e * at1;
        e = v10 + xr0; e = __builtin_elementwise_max(e, e * LRELU_SLOPE); q1 = e * at0;
        e = v11 + xr1; e = __builtin_elementwise_max(e, e * LRELU_SLOPE); q1 += e * at1;
        e = v20 + xr0; e = __builtin_elementwise_max(e, e * LRELU_SLOPE); q2 = e * at0;
        e = v21 + xr1; e = __builtin_elementwise_max(e, e * LRELU_SLOPE); q2 += e * at1;
        e = v30 + xr0; e = __builtin_elementwise_max(e, e * LRELU_SLOPE); q3 = e * at0;
        e = v31 + xr1; e = __builtin_elementwise_max(e, e * LRELU_SLOPE); q3 += e * at1;
        float s0 = row16_sum(q0.x + q0.y);
        float s1 = row16_sum(q1.x + q1.y);
        float s2 = row16_sum(q2.x + q2.y);
        float s3 = row16_sum(q3.x + q3.y);
        if (i + 1 >= r1) s1 = -INFINITY;
        if (i + 2 >= r1) s2 = -INFINITY;
        if (i + 3 >= r1) s3 = -INFINITY;
        const float w0 = fast_exp2(s0), w1 = fast_exp2(s1);
        const float w2 = fast_exp2(s2), w3 = fast_exp2(s3);
        s += (w0 + w1) + (w2 + w3);
        o0 += v00 * w0; o1 += v01 * w0;
        o0 += v10 * w1; o1 += v11 * w1;
        o0 += v20 * w2; o1 += v21 * w2;
        o0 += v30 * w3; o1 += v31 * w3;
      }
      A0 = *(const uint2*)(xl8 + GOFF(i + 8));
      A1 = *(const uint2*)(xl8 + GOFF(i + 9));
      A2 = *(const uint2*)(xl8 + GOFF(i + 10));
      A3 = *(const uint2*)(xl8 + GOFF(i + 11));
      // ---- group B: edges i+4 .. i+7 ----
      {
        const f2 v00 = bfpair(B0.x), v01 = bfpair(B0.y);
        const f2 v10 = bfpair(B1.x), v11 = bfpair(B1.y);
        const f2 v20 = bfpair(B2.x), v21 = bfpair(B2.y);
        const f2 v30 = bfpair(B3.x), v31 = bfpair(B3.y);
        f2 e, q0, q1, q2, q3;
        e = v00 + xr0; e = __builtin_elementwise_max(e, e * LRELU_SLOPE); q0 = e * at0;
        e = v01 + xr1; e = __builtin_elementwise_max(e, e * LRELU_SLOPE); q0 += e * at1;
        e = v10 + xr0; e = __builtin_elementwise_max(e, e * LRELU_SLOPE); q1 = e * at0;
        e = v11 + xr1; e = __builtin_elementwise_max(e, e * LRELU_SLOPE); q1 += e * at1;
        e = v20 + xr0; e = __builtin_elementwise_max(e, e * LRELU_SLOPE); q2 = e * at0;
        e = v21 + xr1; e = __builtin_elementwise_max(e, e * LRELU_SLOPE); q2 += e * at1;
        e = v30 + xr0; e = __builtin_elementwise_max(e, e * LRELU_SLOPE); q3 = e * at0;
        e = v31 + xr1; e = __builtin_elementwise_max(e, e * LRELU_SLOPE); q3 += e * at1;
        float s0 = row16_sum(q0.x + q0.y);
        float s1 = row16_sum(q1.x + q1.y);
        float s2 = row16_sum(q2.x + q2.y);
        float s3 = row16_sum(q3.x + q3.y);
        if (i + 4 >= r1) s0 = -INFINITY;
        if (i + 5 >= r1) s1 = -INFINITY;
        if (i + 6 >= r1) s2 = -INFINITY;
        if (i + 7 >= r1) s3 = -INFINITY;
        const float w0 = fast_exp2(s0), w1 = fast_exp2(s1);
        const float w2 = fast_exp2(s2), w3 = fast_exp2(s3);
        s += (w0 + w1) + (w2 + w3);
        o0 += v00 * w0; o1 += v01 * w0;
        o0 += v10 * w1; o1 += v11 * w1;
        o0 += v20 * w2; o1 += v21 * w2;
        o0 += v30 * w3; o1 += v31 * w3;
      }
      B0 = *(const uint2*)(xl8 + GOFF(i + 12));
      B1 = *(const uint2*)(xl8 + GOFF(i + 13));
      B2 = *(const uint2*)(xl8 + GOFF(i + 14));
      B3 = *(const uint2*)(xl8 + GOFF(i + 15));
    }
#undef GOFF
  }

  const float inv = 1.f / (s + 1e-16f);
  const float4 b4 = *(const float4*)(bo + cb);
  const float v0 = fmaf(o0.x, inv, b4.x);
  const float v1 = fmaf(o0.y, inv, b4.y);
  const float v2 = fmaf(o1.x, inv, b4.z);
  const float v3 = fmaf(o1.y, inv, b4.w);

  float ls = row16_sum(v0 + v1 + v2 + v3);
  ls += __shfl_xor(ls, 16);
  ls += __shfl_xor(ls, 32);
  const float mu = ls * (1.f / 256.f);
  const float d0 = v0 - mu, d1 = v1 - mu, d2 = v2 - mu, d3 = v3 - mu;
  float q = row16_sum(d0 * d0 + d1 * d1 + d2 * d2 + d3 * d3);
  q += __shfl_xor(q, 16);
  q += __shfl_xor(q, 32);
  const float rs = rsqrtf(q * (1.f / 256.f) + 1e-5f);

  const float4 g4 = *(const float4*)(gam + cb);
  const float4 e4 = *(const float4*)(bet + cb);
  ushort4 res;
  res.x = f2bf(fmaf(d0 * rs, g4.x, e4.x));
  res.y = f2bf(fmaf(d1 * rs, g4.y, e4.y));
  res.z = f2bf(fmaf(d2 * rs, g4.z, e4.z));
  res.w = f2bf(fmaf(d3 * rs, g4.w, e4.w));
  *(ushort4*)((char*)outp + (((unsigned)node << 9) + loff)) = res;
}

// ---------------- layer-3 GAT (H=1) + LayerNorm + fused final linear 64->64 ----------------
__global__ __launch_bounds__(512) void gat1_lin(
    const unsigned short* __restrict__ xlb, const unsigned short* __restrict__ xrb,
    const float* __restrict__ att,
    const int* __restrict__ rowptr, const int* __restrict__ csr_src,
    const float* __restrict__ bo, const float* __restrict__ gam,
    const float* __restrict__ bet,
    const float* __restrict__ linW, const float* __restrict__ linb,
    float* __restrict__ outp, int n) {
  const int t = threadIdx.x;
  const int wv = t >> 6, lane = t & 63;
  const int grp = lane >> 3, c8 = lane & 7;
  __shared__ float lw[64][64];
  __shared__ float hbuf[8][64];
  for (int i = t; i < 4096; i += 512) lw[i >> 6][i & 63] = linW[i];

  const int node = blockIdx.x * 8 + wv;
  const bool active = node < n;
  const int cb = c8 * 8;
  const unsigned loff = (unsigned)c8 << 4;
  const char* xl8 = (const char*)xlb;

  f2 xr2[4];
  int r0 = 0, r1 = 0;
  if (active) {
    uint4 p = *(const uint4*)((const char*)xrb + (((unsigned)node << 7) + loff));
    xr2[0] = bfpair(p.x); xr2[1] = bfpair(p.y); xr2[2] = bfpair(p.z); xr2[3] = bfpair(p.w);
    r0 = rowptr[node];
    r1 = rowptr[node + 1];
  } else {
#pragma unroll
    for (int j = 0; j < 4; ++j) xr2[j] = (f2){0.f, 0.f};
  }
  f2 at2[4];
  {
    float4 a0 = *(const float4*)(att + cb);
    float4 a1 = *(const float4*)(att + cb + 4);
    at2[0] = (f2){a0.x * L2E, a0.y * L2E}; at2[1] = (f2){a0.z * L2E, a0.w * L2E};
    at2[2] = (f2){a1.x * L2E, a1.y * L2E}; at2[3] = (f2){a1.z * L2E, a1.w * L2E};
  }

  float s = 0.f;
  f2 o2[4];
#pragma unroll
  for (int j = 0; j < 4; ++j) o2[j] = (f2){0.f, 0.f};

  uint4 vpk = {0u, 0u, 0u, 0u};
  {
    int i0 = r0 + grp;
    if (i0 < r1) vpk = *(const uint4*)(xl8 + ((((unsigned)csr_src[i0]) << 7) + loff));
  }
  bool valid = (r0 + grp) < r1;

  for (int base = r0; base < r1; base += 8) {
    const uint4 pc = vpk;
    const bool vld = valid;
    int inext = base + 8 + grp;
    valid = inext < r1;
    if (valid) vpk = *(const uint4*)(xl8 + ((((unsigned)csr_src[inext]) << 7) + loff));

    f2 v0 = bfpair(pc.x), v1 = bfpair(pc.y), v2 = bfpair(pc.z), v3 = bfpair(pc.w);
    f2 e0 = v0 + xr2[0]; e0 = __builtin_elementwise_max(e0, e0 * LRELU_SLOPE);
    f2 e1 = v1 + xr2[1]; e1 = __builtin_elementwise_max(e1, e1 * LRELU_SLOPE);
    f2 e2 = v2 + xr2[2]; e2 = __builtin_elementwise_max(e2, e2 * LRELU_SLOPE);
    f2 e3 = v3 + xr2[3]; e3 = __builtin_elementwise_max(e3, e3 * LRELU_SLOPE);
    f2 sc2 = e0 * at2[0];
    sc2 += e1 * at2[1];
    sc2 += e2 * at2[2];
    sc2 += e3 * at2[3];
    float sc = sc2.x + sc2.y;
    sc = dpp_add<0xB1>(sc);
    sc = dpp_add<0x4E>(sc);
    sc += __shfl_xor(sc, 4);
    if (!vld) sc = -INFINITY;
    const float w = fast_exp2(sc);
    s += w;
    o2[0] += v0 * w;
    o2[1] += v1 * w;
    o2[2] += v2 * w;
    o2[3] += v3 * w;
  }

  float o[8] = {o2[0].x, o2[0].y, o2[1].x, o2[1].y, o2[2].x, o2[2].y, o2[3].x, o2[3].y};
#pragma unroll
  for (int off = 8; off < 64; off <<= 1) {
#pragma unroll
    for (int i = 0; i < 8; ++i) o[i] += __shfl_xor(o[i], off);
    s += __shfl_xor(s, off);
  }

  const float inv = 1.f / (s + 1e-16f);
  float val[8];
  {
    float4 b0 = *(const float4*)(bo + cb);
    float4 b1 = *(const float4*)(bo + cb + 4);
    val[0] = fmaf(o[0], inv, b0.x); val[1] = fmaf(o[1], inv, b0.y);
    val[2] = fmaf(o[2], inv, b0.z); val[3] = fmaf(o[3], inv, b0.w);
    val[4] = fmaf(o[4], inv, b1.x); val[5] = fmaf(o[5], inv, b1.y);
    val[6] = fmaf(o[6], inv, b1.z); val[7] = fmaf(o[7], inv, b1.w);
  }

  float ls = 0.f;
#pragma unroll
  for (int i = 0; i < 8; ++i) ls += val[i];
  ls = dpp_add<0xB1>(ls);
  ls = dpp_add<0x4E>(ls);
  ls += __shfl_xor(ls, 4);
  float mu = ls * (1.f / 64.f);
  float d[8], q = 0.f;
#pragma unroll
  for (int i = 0; i < 8; ++i) { d[i] = val[i] - mu; q = fmaf(d[i], d[i], q); }
  q = dpp_add<0xB1>(q);
  q = dpp_add<0x4E>(q);
  q += __shfl_xor(q, 4);
  float var = q * (1.f / 64.f);
  const float rs = rsqrtf(var + 1e-5f);

  if (grp == 0) {
    float4 g0 = *(const float4*)(gam + cb);
    float4 g1 = *(const float4*)(gam + cb + 4);
    float4 e0 = *(const float4*)(bet + cb);
    float4 e1 = *(const float4*)(bet + cb + 4);
    float* hb = &hbuf[wv][cb];
    hb[0] = fmaf(d[0] * rs, g0.x, e0.x); hb[1] = fmaf(d[1] * rs, g0.y, e0.y);
    hb[2] = fmaf(d[2] * rs, g0.z, e0.z); hb[3] = fmaf(d[3] * rs, g0.w, e0.w);
    hb[4] = fmaf(d[4] * rs, g1.x, e1.x); hb[5] = fmaf(d[5] * rs, g1.y, e1.y);
    hb[6] = fmaf(d[6] * rs, g1.z, e1.z); hb[7] = fmaf(d[7] * rs, g1.w, e1.w);
  }
  __syncthreads();

  float acc = linb[lane];
#pragma unroll 8
  for (int k = 0; k < 64; ++k) acc = fmaf(hbuf[wv][k], lw[k][lane], acc);
  if (active) outp[(size_t)node * 64 + lane] = acc;
}

extern "C" void kernel_launch(void* const* d_in, const int* in_sizes, int n_in,
                              void* d_out, int out_size, void* d_ws, size_t ws_size,
                              hipStream_t stream) {
  const float* x    = (const float*)d_in[0];
  const int*   eidx = (const int*)d_in[1];
  const int Nn = in_sizes[0] / 128;
  const int Ee = in_sizes[1] / 2;
  const int* src = eidx;
  const int* dst = eidx + Ee;

  const float* W1l = (const float*)d_in[3];  const float* b1l = (const float*)d_in[4];
  const float* W1r = (const float*)d_in[5];  const float* b1r = (const float*)d_in[6];
  const float* a1  = (const float*)d_in[7];  const float* bo1 = (const float*)d_in[8];
  const float* g1  = (const float*)d_in[9];  const float* be1 = (const float*)d_in[10];
  const float* W2l = (const float*)d_in[11]; const float* b2l = (const float*)d_in[12];
  const float* W2r = (const float*)d_in[13]; const float* b2r = (const float*)d_in[14];
  const float* a2  = (const float*)d_in[15]; const float* bo2 = (const float*)d_in[16];
  const float* g2  = (const float*)d_in[17]; const float* be2 = (const float*)d_in[18];
  const float* W3l = (const float*)d_in[19]; const float* b3l = (const float*)d_in[20];
  const float* W3r = (const float*)d_in[21]; const float* b3r = (const float*)d_in[22];
  const float* a3  = (const float*)d_in[23]; const float* bo3 = (const float*)d_in[24];
  const float* g3  = (const float*)d_in[25]; const float* be3 = (const float*)d_in[26];
  const float* linW = (const float*)d_in[27]; const float* linb = (const float*)d_in[28];

  char* ws = (char*)d_ws;
  unsigned short* xl   = (unsigned short*)ws; ws += (size_t)Nn * 256 * 2;
  unsigned short* xr   = (unsigned short*)ws; ws += (size_t)Nn * 256 * 2;
  unsigned short* Xb   = (unsigned short*)ws; ws += (size_t)Nn * 256 * 2;
  unsigned short* Wt1l = (unsigned short*)ws; ws += 256 * 128 * 2;
  unsigned short* Wt1r = (unsigned short*)ws; ws += 256 * 128 * 2;
  unsigned short* Wt2l = (unsigned short*)ws; ws += 256 * 256 * 2;
  unsigned short* Wt2r = (unsigned short*)ws; ws += 256 * 256 * 2;
  unsigned short* Wt3l = (unsigned short*)ws; ws += 64 * 256 * 2;
  unsigned short* Wt3r = (unsigned short*)ws; ws += 64 * 256 * 2;
  int*   deg    = (int*)ws;    ws += (size_t)Nn * 4;
  int*   rowptr = (int*)ws;    ws += (size_t)(Nn + 1) * 4;
  int*   bsum   = (int*)ws;    ws += 1024 * 4;
  int*   boff   = (int*)ws;    ws += 1024 * 4;
  int*   csr_src= (int*)ws;    ws += (size_t)(Ee + 16) * 4;

  const int eblk = (Ee + 255) / 256;
  const int nblk = (Nn + 255) / 256;

  // ---------------- CSR build (by dst) + all weight conversions ----------------
  hipMemsetAsync(deg, 0, (size_t)Nn * 4, stream);
  hist_deg<<<eblk, 256, 0, stream>>>(dst, deg, Ee);
  wt_cvt_all<<<dim3(32, 6), 256, 0, stream>>>(W1l, W1r, W2l, W2r, W3l, W3r,
                                              Wt1l, Wt1r, Wt2l, Wt2r, Wt3l, Wt3r);
  scan_blk<<<nblk, 256, 0, stream>>>(deg, rowptr, bsum, Nn);
  scan_top<<<1, 1024, 0, stream>>>(bsum, boff, rowptr, nblk, Nn);
  scan_add<<<nblk, 256, 0, stream>>>(rowptr, boff, Nn);
  fill_csr<<<(Ee + 16 + 255) / 256, 256, 0, stream>>>(src, dst, rowptr, deg, csr_src, Ee);

  const int gdblk = (Nn + 63) / 64;

  // ---------------- layer 1: 128 -> 4x64 (fused f32->bf16 staging) ----------------
  gemm_dual<128, true><<<gdblk, 512, 0, stream>>>(x, Wt1l, Wt1r, b1l, b1r, xl, xr, Nn);
  gat_fused4<<<(Nn + 3) / 4, 256, 0, stream>>>(xl, xr, a1, rowptr, csr_src, bo1, g1, be1, Xb, Nn);

  // ---------------- layer 2: 256 -> 4x64 ----------------
  gemm_dual<256, false><<<gdblk, 512, 0, stream>>>(Xb, Wt2l, Wt2r, b2l, b2r, xl, xr, Nn);
  gat_fused4<<<(Nn + 3) / 4, 256, 0, stream>>>(xl, xr, a2, rowptr, csr_src, bo2, g2, be2, Xb, Nn);

  // ---------------- layer 3: 256 -> 1x64 + LN + final linear ----------------
  gemm_n64<256><<<dim3(gdblk, 2), 256, 0, stream>>>(Xb, Wt3l, Wt3r, b3l, b3r, xl, xr, Nn);
  gat1_lin<<<(Nn + 7) / 8, 512, 0, stream>>>(xl, xr, a3, rowptr, csr_src, bo3, g3, be3,
                                             linW, linb, (float*)d_out, Nn);
}

// Round 19
// 394.031 us; speedup vs baseline: 1.0154x; 1.0154x over previous
//
#include <hip/hip_runtime.h>
#include <math.h>

#define LRELU_SLOPE 0.2f
#define L2E 1.4426950408889634f

typedef __attribute__((ext_vector_type(8))) short bf16x8;
typedef __attribute__((ext_vector_type(4))) float f32x4;
typedef __attribute__((ext_vector_type(2))) float f2;

__device__ __forceinline__ float fast_exp2(float x) {
  float r; asm("v_exp_f32 %0, %1" : "=v"(r) : "v"(x)); return r;
}

// DPP butterfly add (VALU pipe).
template<int CTRL>
__device__ __forceinline__ float dpp_add(float v) {
  int p = __builtin_amdgcn_update_dpp(0, __float_as_int(v), CTRL, 0xF, 0xF, true);
  return v + __int_as_float(p);
}
__device__ __forceinline__ float row16_sum(float v) {
  v = dpp_add<0xB1>(v);
  v = dpp_add<0x4E>(v);
  v = dpp_add<0x124>(v);
  v = dpp_add<0x128>(v);
  return v;
}

// ---------------- f32 <-> bf16 helpers ----------------
__device__ __forceinline__ unsigned short f2bf(float f) {
  unsigned u = __float_as_uint(f);
  return (unsigned short)((u + 0x7FFFu + ((u >> 16) & 1u)) >> 16);
}
__device__ __forceinline__ f2 bfpair(unsigned p) {
  f2 r;
  r.x = __uint_as_float(p << 16);
  r.y = __uint_as_float(p & 0xffff0000u);
  return r;
}

// all six weight mats W[K][N] f32 -> Wt[N][K] bf16 in one dispatch
__global__ void wt_cvt_all(
    const float* __restrict__ W1l, const float* __restrict__ W1r,
    const float* __restrict__ W2l, const float* __restrict__ W2r,
    const float* __restrict__ W3l, const float* __restrict__ W3r,
    unsigned short* __restrict__ Wt1l, unsigned short* __restrict__ Wt1r,
    unsigned short* __restrict__ Wt2l, unsigned short* __restrict__ Wt2r,
    unsigned short* __restrict__ Wt3l, unsigned short* __restrict__ Wt3r) {
  const float* W; unsigned short* Wt; int K, N;
  switch (blockIdx.y) {
    case 0: W = W1l; Wt = Wt1l; K = 128; N = 256; break;
    case 1: W = W1r; Wt = Wt1r; K = 128; N = 256; break;
    case 2: W = W2l; Wt = Wt2l; K = 256; N = 256; break;
    case 3: W = W2r; Wt = Wt2r; K = 256; N = 256; break;
    case 4: W = W3l; Wt = Wt3l; K = 256; N = 64;  break;
    default: W = W3r; Wt = Wt3r; K = 256; N = 64; break;
  }
  int i = blockIdx.x * blockDim.x + threadIdx.x;
  int k8s = K / 8;
  int n = i / k8s, k8 = i - n * k8s;
  if (n >= N) return;
  unsigned short tmp[8];
#pragma unroll
  for (int j = 0; j < 8; ++j) tmp[j] = f2bf(W[(size_t)(k8 * 8 + j) * N + n]);
  *(bf16x8*)(Wt + (size_t)n * K + k8 * 8) = *(bf16x8*)tmp;
}

// ---------------- dual-side MFMA GEMM, A in LDS, coalesced Y epilogue ----------------
template<int K, bool CVT>
__global__ __launch_bounds__(512) void gemm_dual(
    const void* __restrict__ Xsrc,
    const unsigned short* __restrict__ Wt0, const unsigned short* __restrict__ Wt1,
    const float* __restrict__ bias0, const float* __restrict__ bias1,
    unsigned short* __restrict__ Y0, unsigned short* __restrict__ Y1, int M) {
  constexpr int LDK = K + 8;
  constexpr int SMEM = (64 * LDK > 64 * 256) ? 64 * LDK : 64 * 256;
  __shared__ unsigned short smem[SMEM];
  unsigned short* As = smem;
  const int t = threadIdx.x, w = t >> 6, l = t & 63;
  const int lr = l & 15, lk = l >> 4;
  const int rowBase = blockIdx.x * 64;

  if constexpr (CVT) {
    const float* Xf = (const float*)Xsrc;
    constexpr int SPR = K / 4;
    constexpr int ITER = (64 * SPR) / 512;
#pragma unroll
    for (int i = 0; i < ITER; ++i) {
      int idx = i * 512 + t;
      int row = idx / SPR, seg = idx - row * SPR;
      int gr = rowBase + row; if (gr >= M) gr = M - 1;
      float4 v = *(const float4*)(Xf + (size_t)gr * K + seg * 4);
      ushort4 o;
      o.x = f2bf(v.x); o.y = f2bf(v.y); o.z = f2bf(v.z); o.w = f2bf(v.w);
      *(ushort4*)(As + row * LDK + seg * 4) = o;
    }
  } else {
    const unsigned short* Xb = (const unsigned short*)Xsrc;
    constexpr int SPR = K / 8;
    constexpr int ITER = (64 * SPR) / 512;
#pragma unroll
    for (int i = 0; i < ITER; ++i) {
      int idx = i * 512 + t;
      int row = idx / SPR, seg = idx - row * SPR;
      int gr = rowBase + row; if (gr >= M) gr = M - 1;
      *(uint4*)(As + row * LDK + seg * 8) = *(const uint4*)(Xb + (size_t)gr * K + seg * 8);
    }
  }
  __syncthreads();

  const int side = w >> 2;
  const int n0 = (w & 3) * 64;
  const unsigned short* Wt = side ? Wt1 : Wt0;
  const float* bias = side ? bias1 : bias0;

  f32x4 acc[4][4];
#pragma unroll
  for (int rt = 0; rt < 4; ++rt)
#pragma unroll
    for (int nt = 0; nt < 4; ++nt) acc[rt][nt] = (f32x4){0.f, 0.f, 0.f, 0.f};

  const unsigned short* bp = Wt + (size_t)(n0 + lr) * K + lk * 8;
  const unsigned short* ap = As + lr * LDK + lk * 8;

#pragma unroll
  for (int k0 = 0; k0 < K; k0 += 32) {
    bf16x8 a[4], b[4];
#pragma unroll
    for (int rt = 0; rt < 4; ++rt) a[rt] = *(const bf16x8*)(ap + rt * 16 * LDK + k0);
#pragma unroll
    for (int nt = 0; nt < 4; ++nt) b[nt] = *(const bf16x8*)(bp + nt * 16 * K + k0);
#pragma unroll
    for (int rt = 0; rt < 4; ++rt)
#pragma unroll
      for (int nt = 0; nt < 4; ++nt)
        acc[rt][nt] = __builtin_amdgcn_mfma_f32_16x16x32_bf16(a[rt], b[nt], acc[rt][nt], 0, 0, 0);
  }

  // ---- epilogue: per side, acc -> LDS (bf16) -> full-line stores ----
  unsigned short* ybuf = smem;
#pragma unroll
  for (int sd = 0; sd < 2; ++sd) {
    __syncthreads();
    if (side == sd) {
#pragma unroll
      for (int nt = 0; nt < 4; ++nt) {
        float bv = bias[n0 + nt * 16 + lr];
#pragma unroll
        for (int rt = 0; rt < 4; ++rt)
#pragma unroll
          for (int r = 0; r < 4; ++r)
            ybuf[(rt * 16 + lk * 4 + r) * 256 + n0 + nt * 16 + lr] =
                f2bf(acc[rt][nt][r] + bv);
      }
    }
    __syncthreads();
    unsigned short* Y = sd ? Y1 : Y0;
#pragma unroll
    for (int i = 0; i < 4; ++i) {
      int boff = (i * 512 + t) * 16;
      int row = boff >> 9;
      int col = boff & 511;
      int rg = rowBase + row;
      if (rg < M)
        *(uint4*)((char*)Y + (((size_t)rg << 9) + col)) =
            *(const uint4*)((const char*)ybuf + boff);
    }
  }
}

// ---------------- layer-3 GEMM (N=64 per side), coalesced epilogue ----------------
template<int K>
__global__ __launch_bounds__(256) void gemm_n64(
    const unsigned short* __restrict__ Xb,
    const unsigned short* __restrict__ Wt0, const unsigned short* __restrict__ Wt1,
    const float* __restrict__ bias0, const float* __restrict__ bias1,
    unsigned short* __restrict__ Y0, unsigned short* __restrict__ Y1, int M) {
  __shared__ unsigned short ybuf[64 * 64];
  const int side = blockIdx.y;
  const unsigned short* Wt = side ? Wt1 : Wt0;
  const float* bias = side ? bias1 : bias0;
  unsigned short* Y = side ? Y1 : Y0;
  const int t = threadIdx.x, w = t >> 6, l = t & 63;
  const int lr = l & 15, lk = l >> 4;
  const int rowBase = blockIdx.x * 64 + w * 16;

  f32x4 acc[4];
#pragma unroll
  for (int nt = 0; nt < 4; ++nt) acc[nt] = (f32x4){0.f, 0.f, 0.f, 0.f};

  int arow = rowBase + lr; if (arow >= M) arow = M - 1;
  const unsigned short* ap = Xb + (size_t)arow * K + lk * 8;
  const unsigned short* bp = Wt + (size_t)lr * K + lk * 8;

#pragma unroll
  for (int k0 = 0; k0 < K; k0 += 32) {
    bf16x8 a = *(const bf16x8*)(ap + k0);
    bf16x8 b[4];
#pragma unroll
    for (int nt = 0; nt < 4; ++nt) b[nt] = *(const bf16x8*)(bp + nt * 16 * K + k0);
#pragma unroll
    for (int nt = 0; nt < 4; ++nt)
      acc[nt] = __builtin_amdgcn_mfma_f32_16x16x32_bf16(a, b[nt], acc[nt], 0, 0, 0);
  }

#pragma unroll
  for (int nt = 0; nt < 4; ++nt) {
    float bv = bias[nt * 16 + lr];
#pragma unroll
    for (int r = 0; r < 4; ++r)
      ybuf[(w * 16 + lk * 4 + r) * 64 + nt * 16 + lr] = f2bf(acc[nt][r] + bv);
  }
  __syncthreads();

  const size_t base = (size_t)blockIdx.x * 64 * 64;
#pragma unroll
  for (int i = 0; i < 2; ++i) {
    int idx = i * 256 + t;
    int off = idx * 8;
    int row = off >> 6;
    if (blockIdx.x * 64 + row < M)
      *(uint4*)(Y + base + off) = *(const uint4*)(ybuf + off);
  }
}

// ---------------- CSR build ----------------
__global__ void hist_deg(const int* __restrict__ dst, int* __restrict__ deg, int Ee) {
  int e = blockIdx.x * blockDim.x + threadIdx.x;
  if (e < Ee) atomicAdd(&deg[dst[e]], 1);
}

__global__ void scan_blk(const int* __restrict__ deg, int* __restrict__ rowptr,
                         int* __restrict__ bsum, int n) {
  __shared__ int sm[256];
  const int b = blockIdx.x, t = threadIdx.x;
  const int i = b * 256 + t;
  const int v = (i < n) ? deg[i] : 0;
  sm[t] = v;
  __syncthreads();
#pragma unroll
  for (int off = 1; off < 256; off <<= 1) {
    int x = (t >= off) ? sm[t - off] : 0;
    __syncthreads();
    sm[t] += x;
    __syncthreads();
  }
  if (i < n) rowptr[i] = sm[t] - v;
  if (t == 255) bsum[b] = sm[255];
}

__global__ void scan_top(const int* __restrict__ bsum, int* __restrict__ boff,
                         int* __restrict__ rowptr, int nb, int n) {
  __shared__ int sm[1024];
  const int t = threadIdx.x;
  const int v = (t < nb) ? bsum[t] : 0;
  sm[t] = v;
  __syncthreads();
#pragma unroll
  for (int off = 1; off < 1024; off <<= 1) {
    int x = (t >= off) ? sm[t - off] : 0;
    __syncthreads();
    sm[t] += x;
    __syncthreads();
  }
  if (t < nb) boff[t] = sm[t] - v;
  if (t == 1023) rowptr[n] = sm[1023];
}

__global__ void scan_add(int* __restrict__ rowptr, const int* __restrict__ boff, int n) {
  int i = blockIdx.x * 256 + threadIdx.x;
  if (i < n) rowptr[i] += boff[blockIdx.x];
}

// fill via countdown on deg; pads csr_src[Ee .. Ee+15] with 0 (safe gather target)
__global__ void fill_csr(const int* __restrict__ src, const int* __restrict__ dst,
                         const int* __restrict__ rowptr, int* __restrict__ deg,
                         int* __restrict__ csr_src, int Ee) {
  int e = blockIdx.x * blockDim.x + threadIdx.x;
  if (e < Ee) {
    int d = dst[e];
    int p = atomicSub(&deg[d], 1) - 1;
    csr_src[rowptr[d] + p] = src[e];
  } else if (e < Ee + 16) {
    csr_src[e] = 0;
  }
}

// ---------------- fused GATv2 aggregation + bias + LayerNorm (H=4, bf16 out) ----------------
// ONE WAVE PER NODE: lane = 4 contiguous channels. 4 edges/iter (r15 structure);
// csr_src padded by 16 so prefetch indices need no clamps (OOB edges masked by -INF).
__global__ __launch_bounds__(256) void gat_fused4(
    const unsigned short* __restrict__ xlb, const unsigned short* __restrict__ xrb,
    const float* __restrict__ att,
    const int* __restrict__ rowptr, const int* __restrict__ csr_src,
    const float* __restrict__ bo, const float* __restrict__ gam,
    const float* __restrict__ bet, unsigned short* __restrict__ outp, int n) {
  const int t = threadIdx.x;
  const int wv = t >> 6, lane = t & 63;
  const int node = blockIdx.x * 4 + wv;
  if (node >= n) return;
  const int cb = lane * 4;
  const unsigned loff = (unsigned)lane << 3;
  const char* xl8 = (const char*)xlb;

  uint2 xp = *(const uint2*)((const char*)xrb + (((unsigned)node << 9) + loff));
  const f2 xr0 = bfpair(xp.x), xr1 = bfpair(xp.y);
  const float4 a4 = *(const float4*)(att + cb);
  const f2 at0 = {a4.x * L2E, a4.y * L2E};
  const f2 at1 = {a4.z * L2E, a4.w * L2E};

  const int r0 = rowptr[node], r1 = rowptr[node + 1];
  float s = 0.f;
  f2 o0 = {0.f, 0.f}, o1 = {0.f, 0.f};

  if (r0 < r1) {
#define GOFF(idx) ((((unsigned)csr_src[idx]) << 9) + loff)
    uint2 p0 = *(const uint2*)(xl8 + GOFF(r0));
    uint2 p1 = *(const uint2*)(xl8 + GOFF(r0 + 1));
    uint2 p2 = *(const uint2*)(xl8 + GOFF(r0 + 2));
    uint2 p3 = *(const uint2*)(xl8 + GOFF(r0 + 3));
    for (int i = r0; i < r1; i += 4) {
      const uint2 c0 = p0, c1 = p1, c2 = p2, c3 = p3;
      if (i + 4 < r1) {
        p0 = *(const uint2*)(xl8 + GOFF(i + 4));
        p1 = *(const uint2*)(xl8 + GOFF(i + 5));
        p2 = *(const uint2*)(xl8 + GOFF(i + 6));
        p3 = *(const uint2*)(xl8 + GOFF(i + 7));
      }
      const f2 v00 = bfpair(c0.x), v01 = bfpair(c0.y);
      const f2 v10 = bfpair(c1.x), v11 = bfpair(c1.y);
      const f2 v20 = bfpair(c2.x), v21 = bfpair(c2.y);
      const f2 v30 = bfpair(c3.x), v31 = bfpair(c3.y);

      f2 e;
      f2 q0, q1, q2, q3;
      e = v00 + xr0; e = __builtin_elementwise_max(e, e * LRELU_SLOPE); q0 = e * at0;
      e = v01 + xr1; e = __builtin_elementwise_max(e, e * LRELU_SLOPE); q0 += e * at1;
      e = v10 + xr0; e = __builtin_elementwise_max(e, e * LRELU_SLOPE); q1 = e * at0;
      e = v11 + xr1; e = __builtin_elementwise_max(e, e * LRELU_SLOPE); q1 += e * at1;
      e = v20 + xr0; e = __builtin_elementwise_max(e, e * LRELU_SLOPE); q2 = e * at0;
      e = v21 + xr1; e = __builtin_elementwise_max(e, e * LRELU_SLOPE); q2 += e * at1;
      e = v30 + xr0; e = __builtin_elementwise_max(e, e * LRELU_SLOPE); q3 = e * at0;
      e = v31 + xr1; e = __builtin_elementwise_max(e, e * LRELU_SLOPE); q3 += e * at1;

      float s0 = row16_sum(q0.x + q0.y);
      float s1 = row16_sum(q1.x + q1.y);
      float s2 = row16_sum(q2.x + q2.y);
      float s3 = row16_sum(q3.x + q3.y);
      if (i + 1 >= r1) s1 = -INFINITY;
      if (i + 2 >= r1) s2 = -INFINITY;
      if (i + 3 >= r1) s3 = -INFINITY;
      const float w0 = fast_exp2(s0), w1 = fast_exp2(s1);
      const float w2 = fast_exp2(s2), w3 = fast_exp2(s3);
      s += (w0 + w1) + (w2 + w3);
      o0 += v00 * w0; o1 += v01 * w0;
      o0 += v10 * w1; o1 += v11 * w1;
      o0 += v20 * w2; o1 += v21 * w2;
      o0 += v30 * w3; o1 += v31 * w3;
    }
#undef GOFF
  }

  const float inv = 1.f / (s + 1e-16f);
  const float4 b4 = *(const float4*)(bo + cb);
  const float v0 = fmaf(o0.x, inv, b4.x);
  const float v1 = fmaf(o0.y, inv, b4.y);
  const float v2 = fmaf(o1.x, inv, b4.z);
  const float v3 = fmaf(o1.y, inv, b4.w);

  float ls = row16_sum(v0 + v1 + v2 + v3);
  ls += __shfl_xor(ls, 16);
  ls += __shfl_xor(ls, 32);
  const float mu = ls * (1.f / 256.f);
  const float d0 = v0 - mu, d1 = v1 - mu, d2 = v2 - mu, d3 = v3 - mu;
  float q = row16_sum(d0 * d0 + d1 * d1 + d2 * d2 + d3 * d3);
  q += __shfl_xor(q, 16);
  q += __shfl_xor(q, 32);
  const float rs = rsqrtf(q * (1.f / 256.f) + 1e-5f);

  const float4 g4 = *(const float4*)(gam + cb);
  const float4 e4 = *(const float4*)(bet + cb);
  ushort4 res;
  res.x = f2bf(fmaf(d0 * rs, g4.x, e4.x));
  res.y = f2bf(fmaf(d1 * rs, g4.y, e4.y));
  res.z = f2bf(fmaf(d2 * rs, g4.z, e4.z));
  res.w = f2bf(fmaf(d3 * rs, g4.w, e4.w));
  *(ushort4*)((char*)outp + (((unsigned)node << 9) + loff)) = res;
}

// ---------------- layer-3 GAT (H=1) + LayerNorm + fused final linear 64->64 ----------------
__global__ __launch_bounds__(512) void gat1_lin(
    const unsigned short* __restrict__ xlb, const unsigned short* __restrict__ xrb,
    const float* __restrict__ att,
    const int* __restrict__ rowptr, const int* __restrict__ csr_src,
    const float* __restrict__ bo, const float* __restrict__ gam,
    const float* __restrict__ bet,
    const float* __restrict__ linW, const float* __restrict__ linb,
    float* __restrict__ outp, int n) {
  const int t = threadIdx.x;
  const int wv = t >> 6, lane = t & 63;
  const int grp = lane >> 3, c8 = lane & 7;
  __shared__ float lw[64][64];
  __shared__ float hbuf[8][64];
  for (int i = t; i < 4096; i += 512) lw[i >> 6][i & 63] = linW[i];

  const int node = blockIdx.x * 8 + wv;
  const bool active = node < n;
  const int cb = c8 * 8;
  const unsigned loff = (unsigned)c8 << 4;
  const char* xl8 = (const char*)xlb;

  f2 xr2[4];
  int r0 = 0, r1 = 0;
  if (active) {
    uint4 p = *(const uint4*)((const char*)xrb + (((unsigned)node << 7) + loff));
    xr2[0] = bfpair(p.x); xr2[1] = bfpair(p.y); xr2[2] = bfpair(p.z); xr2[3] = bfpair(p.w);
    r0 = rowptr[node];
    r1 = rowptr[node + 1];
  } else {
#pragma unroll
    for (int j = 0; j < 4; ++j) xr2[j] = (f2){0.f, 0.f};
  }
  f2 at2[4];
  {
    float4 a0 = *(const float4*)(att + cb);
    float4 a1 = *(const float4*)(att + cb + 4);
    at2[0] = (f2){a0.x * L2E, a0.y * L2E}; at2[1] = (f2){a0.z * L2E, a0.w * L2E};
    at2[2] = (f2){a1.x * L2E, a1.y * L2E}; at2[3] = (f2){a1.z * L2E, a1.w * L2E};
  }

  float s = 0.f;
  f2 o2[4];
#pragma unroll
  for (int j = 0; j < 4; ++j) o2[j] = (f2){0.f, 0.f};

  uint4 vpk = {0u, 0u, 0u, 0u};
  {
    int i0 = r0 + grp;
    if (i0 < r1) vpk = *(const uint4*)(xl8 + ((((unsigned)csr_src[i0]) << 7) + loff));
  }
  bool valid = (r0 + grp) < r1;

  for (int base = r0; base < r1; base += 8) {
    const uint4 pc = vpk;
    const bool vld = valid;
    int inext = base + 8 + grp;
    valid = inext < r1;
    if (valid) vpk = *(const uint4*)(xl8 + ((((unsigned)csr_src[inext]) << 7) + loff));

    f2 v0 = bfpair(pc.x), v1 = bfpair(pc.y), v2 = bfpair(pc.z), v3 = bfpair(pc.w);
    f2 e0 = v0 + xr2[0]; e0 = __builtin_elementwise_max(e0, e0 * LRELU_SLOPE);
    f2 e1 = v1 + xr2[1]; e1 = __builtin_elementwise_max(e1, e1 * LRELU_SLOPE);
    f2 e2 = v2 + xr2[2]; e2 = __builtin_elementwise_max(e2, e2 * LRELU_SLOPE);
    f2 e3 = v3 + xr2[3]; e3 = __builtin_elementwise_max(e3, e3 * LRELU_SLOPE);
    f2 sc2 = e0 * at2[0];
    sc2 += e1 * at2[1];
    sc2 += e2 * at2[2];
    sc2 += e3 * at2[3];
    float sc = sc2.x + sc2.y;
    sc = dpp_add<0xB1>(sc);
    sc = dpp_add<0x4E>(sc);
    sc += __shfl_xor(sc, 4);
    if (!vld) sc = -INFINITY;
    const float w = fast_exp2(sc);
    s += w;
    o2[0] += v0 * w;
    o2[1] += v1 * w;
    o2[2] += v2 * w;
    o2[3] += v3 * w;
  }

  float o[8] = {o2[0].x, o2[0].y, o2[1].x, o2[1].y, o2[2].x, o2[2].y, o2[3].x, o2[3].y};
#pragma unroll
  for (int off = 8; off < 64; off <<= 1) {
#pragma unroll
    for (int i = 0; i < 8; ++i) o[i] += __shfl_xor(o[i], off);
    s += __shfl_xor(s, off);
  }

  const float inv = 1.f / (s + 1e-16f);
  float val[8];
  {
    float4 b0 = *(const float4*)(bo + cb);
    float4 b1 = *(const float4*)(bo + cb + 4);
    val[0] = fmaf(o[0], inv, b0.x); val[1] = fmaf(o[1], inv, b0.y);
    val[2] = fmaf(o[2], inv, b0.z); val[3] = fmaf(o[3], inv, b0.w);
    val[4] = fmaf(o[4], inv, b1.x); val[5] = fmaf(o[5], inv, b1.y);
    val[6] = fmaf(o[6], inv, b1.z); val[7] = fmaf(o[7], inv, b1.w);
  }

  float ls = 0.f;
#pragma unroll
  for (int i = 0; i < 8; ++i) ls += val[i];
  ls = dpp_add<0xB1>(ls);
  ls = dpp_add<0x4E>(ls);
  ls += __shfl_xor(ls, 4);
  float mu = ls * (1.f / 64.f);
  float d[8], q = 0.f;
#pragma unroll
  for (int i = 0; i < 8; ++i) { d[i] = val[i] - mu; q = fmaf(d[i], d[i], q); }
  q = dpp_add<0xB1>(q);
  q = dpp_add<0x4E>(q);
  q += __shfl_xor(q, 4);
  float var = q * (1.f / 64.f);
  const float rs = rsqrtf(var + 1e-5f);

  if (grp == 0) {
    float4 g0 = *(const float4*)(gam + cb);
    float4 g1 = *(const float4*)(gam + cb + 4);
    float4 e0 = *(const float4*)(bet + cb);
    float4 e1 = *(const float4*)(bet + cb + 4);
    float* hb = &hbuf[wv][cb];
    hb[0] = fmaf(d[0] * rs, g0.x, e0.x); hb[1] = fmaf(d[1] * rs, g0.y, e0.y);
    hb[2] = fmaf(d[2] * rs, g0.z, e0.z); hb[3] = fmaf(d[3] * rs, g0.w, e0.w);
    hb[4] = fmaf(d[4] * rs, g1.x, e1.x); hb[5] = fmaf(d[5] * rs, g1.y, e1.y);
    hb[6] = fmaf(d[6] * rs, g1.z, e1.z); hb[7] = fmaf(d[7] * rs, g1.w, e1.w);
  }
  __syncthreads();

  float acc = linb[lane];
#pragma unroll 8
  for (int k = 0; k < 64; ++k) acc = fmaf(hbuf[wv][k], lw[k][lane], acc);
  if (active) outp[(size_t)node * 64 + lane] = acc;
}

extern "C" void kernel_launch(void* const* d_in, const int* in_sizes, int n_in,
                              void* d_out, int out_size, void* d_ws, size_t ws_size,
                              hipStream_t stream) {
  const float* x    = (const float*)d_in[0];
  const int*   eidx = (const int*)d_in[1];
  const int Nn = in_sizes[0] / 128;
  const int Ee = in_sizes[1] / 2;
  const int* src = eidx;
  const int* dst = eidx + Ee;

  const float* W1l = (const float*)d_in[3];  const float* b1l = (const float*)d_in[4];
  const float* W1r = (const float*)d_in[5];  const float* b1r = (const float*)d_in[6];
  const float* a1  = (const float*)d_in[7];  const float* bo1 = (const float*)d_in[8];
  const float* g1  = (const float*)d_in[9];  const float* be1 = (const float*)d_in[10];
  const float* W2l = (const float*)d_in[11]; const float* b2l = (const float*)d_in[12];
  const float* W2r = (const float*)d_in[13]; const float* b2r = (const float*)d_in[14];
  const float* a2  = (const float*)d_in[15]; const float* bo2 = (const float*)d_in[16];
  const float* g2  = (const float*)d_in[17]; const float* be2 = (const float*)d_in[18];
  const float* W3l = (const float*)d_in[19]; const float* b3l = (const float*)d_in[20];
  const float* W3r = (const float*)d_in[21]; const float* b3r = (const float*)d_in[22];
  const float* a3  = (const float*)d_in[23]; const float* bo3 = (const float*)d_in[24];
  const float* g3  = (const float*)d_in[25]; const float* be3 = (const float*)d_in[26];
  const float* linW = (const float*)d_in[27]; const float* linb = (const float*)d_in[28];

  char* ws = (char*)d_ws;
  unsigned short* xl   = (unsigned short*)ws; ws += (size_t)Nn * 256 * 2;
  unsigned short* xr   = (unsigned short*)ws; ws += (size_t)Nn * 256 * 2;
  unsigned short* Xb   = (unsigned short*)ws; ws += (size_t)Nn * 256 * 2;
  unsigned short* Wt1l = (unsigned short*)ws; ws += 256 * 128 * 2;
  unsigned short* Wt1r = (unsigned short*)ws; ws += 256 * 128 * 2;
  unsigned short* Wt2l = (unsigned short*)ws; ws += 256 * 256 * 2;
  unsigned short* Wt2r = (unsigned short*)ws; ws += 256 * 256 * 2;
  unsigned short* Wt3l = (unsigned short*)ws; ws += 64 * 256 * 2;
  unsigned short* Wt3r = (unsigned short*)ws; ws += 64 * 256 * 2;
  int*   deg    = (int*)ws;    ws += (size_t)Nn * 4;
  int*   rowptr = (int*)ws;    ws += (size_t)(Nn + 1) * 4;
  int*   bsum   = (int*)ws;    ws += 1024 * 4;
  int*   boff   = (int*)ws;    ws += 1024 * 4;
  int*   csr_src= (int*)ws;    ws += (size_t)(Ee + 16) * 4;

  const int eblk = (Ee + 255) / 256;
  const int nblk = (Nn + 255) / 256;

  // ---------------- CSR build (by dst) + all weight conversions ----------------
  hipMemsetAsync(deg, 0, (size_t)Nn * 4, stream);
  hist_deg<<<eblk, 256, 0, stream>>>(dst, deg, Ee);
  wt_cvt_all<<<dim3(32, 6), 256, 0, stream>>>(W1l, W1r, W2l, W2r, W3l, W3r,
                                              Wt1l, Wt1r, Wt2l, Wt2r, Wt3l, Wt3r);
  scan_blk<<<nblk, 256, 0, stream>>>(deg, rowptr, bsum, Nn);
  scan_top<<<1, 1024, 0, stream>>>(bsum, boff, rowptr, nblk, Nn);
  scan_add<<<nblk, 256, 0, stream>>>(rowptr, boff, Nn);
  fill_csr<<<(Ee + 16 + 255) / 256, 256, 0, stream>>>(src, dst, rowptr, deg, csr_src, Ee);

  const int gdblk = (Nn + 63) / 64;

  // ---------------- layer 1: 128 -> 4x64 (fused f32->bf16 staging) ----------------
  gemm_dual<128, true><<<gdblk, 512, 0, stream>>>(x, Wt1l, Wt1r, b1l, b1r, xl, xr, Nn);
  gat_fused4<<<(Nn + 3) / 4, 256, 0, stream>>>(xl, xr, a1, rowptr, csr_src, bo1, g1, be1, Xb, Nn);

  // ---------------- layer 2: 256 -> 4x64 ----------------
  gemm_dual<256, false><<<gdblk, 512, 0, stream>>>(Xb, Wt2l, Wt2r, b2l, b2r, xl, xr, Nn);
  gat_fused4<<<(Nn + 3) / 4, 256, 0, stream>>>(xl, xr, a2, rowptr, csr_src, bo2, g2, be2, Xb, Nn);

  // ---------------- layer 3: 256 -> 1x64 + LN + final linear ----------------
  gemm_n64<256><<<dim3(gdblk, 2), 256, 0, stream>>>(Xb, Wt3l, Wt3r, b3l, b3r, xl, xr, Nn);
  gat1_lin<<<(Nn + 7) / 8, 512, 0, stream>>>(xl, xr, a3, rowptr, csr_src, bo3, g3, be3,
                                             linW, linb, (float*)d_out, Nn);
}

// Round 20
// 373.424 us; speedup vs baseline: 1.0715x; 1.0552x over previous
//
#include <hip/hip_runtime.h>
#include <math.h>

#define LRELU_SLOPE 0.2f
#define L2E 1.4426950408889634f

typedef __attribute__((ext_vector_type(8))) short bf16x8;
typedef __attribute__((ext_vector_type(4))) float f32x4;
typedef __attribute__((ext_vector_type(2))) float f2;

__device__ __forceinline__ float fast_exp2(float x) {
  float r; asm("v_exp_f32 %0, %1" : "=v"(r) : "v"(x)); return r;
}

// DPP butterfly add (VALU pipe).
template<int CTRL>
__device__ __forceinline__ float dpp_add(float v) {
  int p = __builtin_amdgcn_update_dpp(0, __float_as_int(v), CTRL, 0xF, 0xF, true);
  return v + __int_as_float(p);
}
__device__ __forceinline__ float row16_sum(float v) {
  v = dpp_add<0xB1>(v);
  v = dpp_add<0x4E>(v);
  v = dpp_add<0x124>(v);
  v = dpp_add<0x128>(v);
  return v;
}

// ---------------- f32 <-> bf16 helpers ----------------
__device__ __forceinline__ unsigned short f2bf(float f) {
  unsigned u = __float_as_uint(f);
  return (unsigned short)((u + 0x7FFFu + ((u >> 16) & 1u)) >> 16);
}
__device__ __forceinline__ f2 bfpair(unsigned p) {
  f2 r;
  r.x = __uint_as_float(p << 16);
  r.y = __uint_as_float(p & 0xffff0000u);
  return r;
}

// all six weight mats W[K][N] f32 -> Wt[N][K] bf16 in one dispatch
__global__ void wt_cvt_all(
    const float* __restrict__ W1l, const float* __restrict__ W1r,
    const float* __restrict__ W2l, const float* __restrict__ W2r,
    const float* __restrict__ W3l, const float* __restrict__ W3r,
    unsigned short* __restrict__ Wt1l, unsigned short* __restrict__ Wt1r,
    unsigned short* __restrict__ Wt2l, unsigned short* __restrict__ Wt2r,
    unsigned short* __restrict__ Wt3l, unsigned short* __restrict__ Wt3r) {
  const float* W; unsigned short* Wt; int K, N;
  switch (blockIdx.y) {
    case 0: W = W1l; Wt = Wt1l; K = 128; N = 256; break;
    case 1: W = W1r; Wt = Wt1r; K = 128; N = 256; break;
    case 2: W = W2l; Wt = Wt2l; K = 256; N = 256; break;
    case 3: W = W2r; Wt = Wt2r; K = 256; N = 256; break;
    case 4: W = W3l; Wt = Wt3l; K = 256; N = 64;  break;
    default: W = W3r; Wt = Wt3r; K = 256; N = 64; break;
  }
  int i = blockIdx.x * blockDim.x + threadIdx.x;
  int k8s = K / 8;
  int n = i / k8s, k8 = i - n * k8s;
  if (n >= N) return;
  unsigned short tmp[8];
#pragma unroll
  for (int j = 0; j < 8; ++j) tmp[j] = f2bf(W[(size_t)(k8 * 8 + j) * N + n]);
  *(bf16x8*)(Wt + (size_t)n * K + k8 * 8) = *(bf16x8*)tmp;
}

// ---------------- per-side MFMA GEMM, A in LDS, coalesced Y epilogue ----------------
// grid (ceil(M/64), 2): y = side. 256 thr = 4 waves; wave w -> col strip w*64.
// A-tile (64 x K) staged in LDS; B streams from L2; epilogue via LDS full-line stores.
template<int K, bool CVT>
__global__ __launch_bounds__(256) void gemm_side(
    const void* __restrict__ Xsrc,
    const unsigned short* __restrict__ Wt0, const unsigned short* __restrict__ Wt1,
    const float* __restrict__ bias0, const float* __restrict__ bias1,
    unsigned short* __restrict__ Y0, unsigned short* __restrict__ Y1, int M) {
  constexpr int LDK = K + 8;
  constexpr int SMEM = (64 * LDK > 64 * 256) ? 64 * LDK : 64 * 256;
  __shared__ unsigned short smem[SMEM];
  unsigned short* As = smem;
  const int t = threadIdx.x, w = t >> 6, l = t & 63;
  const int lr = l & 15, lk = l >> 4;
  const int rowBase = blockIdx.x * 64;
  const int side = blockIdx.y;
  const unsigned short* Wt = side ? Wt1 : Wt0;
  const float* bias = side ? bias1 : bias0;
  unsigned short* Y = side ? Y1 : Y0;

  if constexpr (CVT) {
    const float* Xf = (const float*)Xsrc;
    constexpr int SPR = K / 4;
    constexpr int ITER = (64 * SPR) / 256;
#pragma unroll
    for (int i = 0; i < ITER; ++i) {
      int idx = i * 256 + t;
      int row = idx / SPR, seg = idx - row * SPR;
      int gr = rowBase + row; if (gr >= M) gr = M - 1;
      float4 v = *(const float4*)(Xf + (size_t)gr * K + seg * 4);
      ushort4 o;
      o.x = f2bf(v.x); o.y = f2bf(v.y); o.z = f2bf(v.z); o.w = f2bf(v.w);
      *(ushort4*)(As + row * LDK + seg * 4) = o;
    }
  } else {
    const unsigned short* Xb = (const unsigned short*)Xsrc;
    constexpr int SPR = K / 8;
    constexpr int ITER = (64 * SPR) / 256;
#pragma unroll
    for (int i = 0; i < ITER; ++i) {
      int idx = i * 256 + t;
      int row = idx / SPR, seg = idx - row * SPR;
      int gr = rowBase + row; if (gr >= M) gr = M - 1;
      *(uint4*)(As + row * LDK + seg * 8) = *(const uint4*)(Xb + (size_t)gr * K + seg * 8);
    }
  }
  __syncthreads();

  const int n0 = w * 64;

  f32x4 acc[4][4];
#pragma unroll
  for (int rt = 0; rt < 4; ++rt)
#pragma unroll
    for (int nt = 0; nt < 4; ++nt) acc[rt][nt] = (f32x4){0.f, 0.f, 0.f, 0.f};

  const unsigned short* bp = Wt + (size_t)(n0 + lr) * K + lk * 8;
  const unsigned short* ap = As + lr * LDK + lk * 8;

#pragma unroll
  for (int k0 = 0; k0 < K; k0 += 32) {
    bf16x8 a[4], b[4];
#pragma unroll
    for (int rt = 0; rt < 4; ++rt) a[rt] = *(const bf16x8*)(ap + rt * 16 * LDK + k0);
#pragma unroll
    for (int nt = 0; nt < 4; ++nt) b[nt] = *(const bf16x8*)(bp + nt * 16 * K + k0);
#pragma unroll
    for (int rt = 0; rt < 4; ++rt)
#pragma unroll
      for (int nt = 0; nt < 4; ++nt)
        acc[rt][nt] = __builtin_amdgcn_mfma_f32_16x16x32_bf16(a[rt], b[nt], acc[rt][nt], 0, 0, 0);
  }

  // ---- epilogue: acc -> LDS (bf16) -> full-line stores ----
  unsigned short* ybuf = smem;   // alias As
  __syncthreads();
#pragma unroll
  for (int nt = 0; nt < 4; ++nt) {
    float bv = bias[n0 + nt * 16 + lr];
#pragma unroll
    for (int rt = 0; rt < 4; ++rt)
#pragma unroll
      for (int r = 0; r < 4; ++r)
        ybuf[(rt * 16 + lk * 4 + r) * 256 + n0 + nt * 16 + lr] =
            f2bf(acc[rt][nt][r] + bv);
  }
  __syncthreads();
#pragma unroll
  for (int i = 0; i < 8; ++i) {
    int boff = (i * 256 + t) * 16;
    int row = boff >> 9;
    int col = boff & 511;
    int rg = rowBase + row;
    if (rg < M)
      *(uint4*)((char*)Y + (((size_t)rg << 9) + col)) =
          *(const uint4*)((const char*)ybuf + boff);
  }
}

// ---------------- layer-3 GEMM (N=64 per side), coalesced epilogue ----------------
template<int K>
__global__ __launch_bounds__(256) void gemm_n64(
    const unsigned short* __restrict__ Xb,
    const unsigned short* __restrict__ Wt0, const unsigned short* __restrict__ Wt1,
    const float* __restrict__ bias0, const float* __restrict__ bias1,
    unsigned short* __restrict__ Y0, unsigned short* __restrict__ Y1, int M) {
  __shared__ unsigned short ybuf[64 * 64];
  const int side = blockIdx.y;
  const unsigned short* Wt = side ? Wt1 : Wt0;
  const float* bias = side ? bias1 : bias0;
  unsigned short* Y = side ? Y1 : Y0;
  const int t = threadIdx.x, w = t >> 6, l = t & 63;
  const int lr = l & 15, lk = l >> 4;
  const int rowBase = blockIdx.x * 64 + w * 16;

  f32x4 acc[4];
#pragma unroll
  for (int nt = 0; nt < 4; ++nt) acc[nt] = (f32x4){0.f, 0.f, 0.f, 0.f};

  int arow = rowBase + lr; if (arow >= M) arow = M - 1;
  const unsigned short* ap = Xb + (size_t)arow * K + lk * 8;
  const unsigned short* bp = Wt + (size_t)lr * K + lk * 8;

#pragma unroll
  for (int k0 = 0; k0 < K; k0 += 32) {
    bf16x8 a = *(const bf16x8*)(ap + k0);
    bf16x8 b[4];
#pragma unroll
    for (int nt = 0; nt < 4; ++nt) b[nt] = *(const bf16x8*)(bp + nt * 16 * K + k0);
#pragma unroll
    for (int nt = 0; nt < 4; ++nt)
      acc[nt] = __builtin_amdgcn_mfma_f32_16x16x32_bf16(a, b[nt], acc[nt], 0, 0, 0);
  }

#pragma unroll
  for (int nt = 0; nt < 4; ++nt) {
    float bv = bias[nt * 16 + lr];
#pragma unroll
    for (int r = 0; r < 4; ++r)
      ybuf[(w * 16 + lk * 4 + r) * 64 + nt * 16 + lr] = f2bf(acc[nt][r] + bv);
  }
  __syncthreads();

  const size_t base = (size_t)blockIdx.x * 64 * 64;
#pragma unroll
  for (int i = 0; i < 2; ++i) {
    int idx = i * 256 + t;
    int off = idx * 8;
    int row = off >> 6;
    if (blockIdx.x * 64 + row < M)
      *(uint4*)(Y + base + off) = *(const uint4*)(ybuf + off);
  }
}

// ---------------- CSR build ----------------
__global__ void hist_deg(const int* __restrict__ dst, int* __restrict__ deg, int Ee) {
  int e = blockIdx.x * blockDim.x + threadIdx.x;
  if (e < Ee) atomicAdd(&deg[dst[e]], 1);
}

__global__ void scan_blk(const int* __restrict__ deg, int* __restrict__ rowptr,
                         int* __restrict__ bsum, int n) {
  __shared__ int sm[256];
  const int b = blockIdx.x, t = threadIdx.x;
  const int i = b * 256 + t;
  const int v = (i < n) ? deg[i] : 0;
  sm[t] = v;
  __syncthreads();
#pragma unroll
  for (int off = 1; off < 256; off <<= 1) {
    int x = (t >= off) ? sm[t - off] : 0;
    __syncthreads();
    sm[t] += x;
    __syncthreads();
  }
  if (i < n) rowptr[i] = sm[t] - v;
  if (t == 255) bsum[b] = sm[255];
}

__global__ void scan_top(const int* __restrict__ bsum, int* __restrict__ boff,
                         int* __restrict__ rowptr, int nb, int n) {
  __shared__ int sm[1024];
  const int t = threadIdx.x;
  const int v = (t < nb) ? bsum[t] : 0;
  sm[t] = v;
  __syncthreads();
#pragma unroll
  for (int off = 1; off < 1024; off <<= 1) {
    int x = (t >= off) ? sm[t - off] : 0;
    __syncthreads();
    sm[t] += x;
    __syncthreads();
  }
  if (t < nb) boff[t] = sm[t] - v;
  if (t == 1023) rowptr[n] = sm[1023];
}

__global__ void scan_add(int* __restrict__ rowptr, const int* __restrict__ boff, int n) {
  int i = blockIdx.x * 256 + threadIdx.x;
  if (i < n) rowptr[i] += boff[blockIdx.x];
}

// fill via countdown on deg; pads csr_src[Ee .. Ee+15] with 0 (safe gather target)
__global__ void fill_csr(const int* __restrict__ src, const int* __restrict__ dst,
                         const int* __restrict__ rowptr, int* __restrict__ deg,
                         int* __restrict__ csr_src, int Ee) {
  int e = blockIdx.x * blockDim.x + threadIdx.x;
  if (e < Ee) {
    int d = dst[e];
    int p = atomicSub(&deg[d], 1) - 1;
    csr_src[rowptr[d] + p] = src[e];
  } else if (e < Ee + 16) {
    csr_src[e] = 0;
  }
}

// ---------------- fused GATv2 aggregation + bias + LayerNorm (H=4, bf16 out) ----------------
// ONE WAVE PER NODE: lane = 4 contiguous channels. 4 edges/iter; padded csr_src (no clamps).
__global__ __launch_bounds__(256) void gat_fused4(
    const unsigned short* __restrict__ xlb, const unsigned short* __restrict__ xrb,
    const float* __restrict__ att,
    const int* __restrict__ rowptr, const int* __restrict__ csr_src,
    const float* __restrict__ bo, const float* __restrict__ gam,
    const float* __restrict__ bet, unsigned short* __restrict__ outp, int n) {
  const int t = threadIdx.x;
  const int wv = t >> 6, lane = t & 63;
  const int node = blockIdx.x * 4 + wv;
  if (node >= n) return;
  const int cb = lane * 4;
  const unsigned loff = (unsigned)lane << 3;
  const char* xl8 = (const char*)xlb;

  uint2 xp = *(const uint2*)((const char*)xrb + (((unsigned)node << 9) + loff));
  const f2 xr0 = bfpair(xp.x), xr1 = bfpair(xp.y);
  const float4 a4 = *(const float4*)(att + cb);
  const f2 at0 = {a4.x * L2E, a4.y * L2E};
  const f2 at1 = {a4.z * L2E, a4.w * L2E};

  const int r0 = rowptr[node], r1 = rowptr[node + 1];
  float s = 0.f;
  f2 o0 = {0.f, 0.f}, o1 = {0.f, 0.f};

  if (r0 < r1) {
#define GOFF(idx) ((((unsigned)csr_src[idx]) << 9) + loff)
    uint2 p0 = *(const uint2*)(xl8 + GOFF(r0));
    uint2 p1 = *(const uint2*)(xl8 + GOFF(r0 + 1));
    uint2 p2 = *(const uint2*)(xl8 + GOFF(r0 + 2));
    uint2 p3 = *(const uint2*)(xl8 + GOFF(r0 + 3));
    for (int i = r0; i < r1; i += 4) {
      const uint2 c0 = p0, c1 = p1, c2 = p2, c3 = p3;
      if (i + 4 < r1) {
        p0 = *(const uint2*)(xl8 + GOFF(i + 4));
        p1 = *(const uint2*)(xl8 + GOFF(i + 5));
        p2 = *(const uint2*)(xl8 + GOFF(i + 6));
        p3 = *(const uint2*)(xl8 + GOFF(i + 7));
      }
      const f2 v00 = bfpair(c0.x), v01 = bfpair(c0.y);
      const f2 v10 = bfpair(c1.x), v11 = bfpair(c1.y);
      const f2 v20 = bfpair(c2.x), v21 = bfpair(c2.y);
      const f2 v30 = bfpair(c3.x), v31 = bfpair(c3.y);

      f2 e;
      f2 q0, q1, q2, q3;
      e = v00 + xr0; e = __builtin_elementwise_max(e, e * LRELU_SLOPE); q0 = e * at0;
      e = v01 + xr1; e = __builtin_elementwise_max(e, e * LRELU_SLOPE); q0 += e * at1;
      e = v10 + xr0; e = __builtin_elementwise_max(e, e * LRELU_SLOPE); q1 = e * at0;
      e = v11 + xr1; e = __builtin_elementwise_max(e, e * LRELU_SLOPE); q1 += e * at1;
      e = v20 + xr0; e = __builtin_elementwise_max(e, e * LRELU_SLOPE); q2 = e * at0;
      e = v21 + xr1; e = __builtin_elementwise_max(e, e * LRELU_SLOPE); q2 += e * at1;
      e = v30 + xr0; e = __builtin_elementwise_max(e, e * LRELU_SLOPE); q3 = e * at0;
      e = v31 + xr1; e = __builtin_elementwise_max(e, e * LRELU_SLOPE); q3 += e * at1;

      float s0 = row16_sum(q0.x + q0.y);
      float s1 = row16_sum(q1.x + q1.y);
      float s2 = row16_sum(q2.x + q2.y);
      float s3 = row16_sum(q3.x + q3.y);
      if (i + 1 >= r1) s1 = -INFINITY;
      if (i + 2 >= r1) s2 = -INFINITY;
      if (i + 3 >= r1) s3 = -INFINITY;
      const float w0 = fast_exp2(s0), w1 = fast_exp2(s1);
      const float w2 = fast_exp2(s2), w3 = fast_exp2(s3);
      s += (w0 + w1) + (w2 + w3);
      o0 += v00 * w0; o1 += v01 * w0;
      o0 += v10 * w1; o1 += v11 * w1;
      o0 += v20 * w2; o1 += v21 * w2;
      o0 += v30 * w3; o1 += v31 * w3;
    }
#undef GOFF
  }

  const float inv = 1.f / (s + 1e-16f);
  const float4 b4 = *(const float4*)(bo + cb);
  const float v0 = fmaf(o0.x, inv, b4.x);
  const float v1 = fmaf(o0.y, inv, b4.y);
  const float v2 = fmaf(o1.x, inv, b4.z);
  const float v3 = fmaf(o1.y, inv, b4.w);

  float ls = row16_sum(v0 + v1 + v2 + v3);
  ls += __shfl_xor(ls, 16);
  ls += __shfl_xor(ls, 32);
  const float mu = ls * (1.f / 256.f);
  const float d0 = v0 - mu, d1 = v1 - mu, d2 = v2 - mu, d3 = v3 - mu;
  float q = row16_sum(d0 * d0 + d1 * d1 + d2 * d2 + d3 * d3);
  q += __shfl_xor(q, 16);
  q += __shfl_xor(q, 32);
  const float rs = rsqrtf(q * (1.f / 256.f) + 1e-5f);

  const float4 g4 = *(const float4*)(gam + cb);
  const float4 e4 = *(const float4*)(bet + cb);
  ushort4 res;
  res.x = f2bf(fmaf(d0 * rs, g4.x, e4.x));
  res.y = f2bf(fmaf(d1 * rs, g4.y, e4.y));
  res.z = f2bf(fmaf(d2 * rs, g4.z, e4.z));
  res.w = f2bf(fmaf(d3 * rs, g4.w, e4.w));
  *(ushort4*)((char*)outp + (((unsigned)node << 9) + loff)) = res;
}

// ---------------- layer-3 GAT (H=1) + LayerNorm + fused final linear 64->64 ----------------
__global__ __launch_bounds__(512) void gat1_lin(
    const unsigned short* __restrict__ xlb, const unsigned short* __restrict__ xrb,
    const float* __restrict__ att,
    const int* __restrict__ rowptr, const int* __restrict__ csr_src,
    const float* __restrict__ bo, const float* __restrict__ gam,
    const float* __restrict__ bet,
    const float* __restrict__ linW, const float* __restrict__ linb,
    float* __restrict__ outp, int n) {
  const int t = threadIdx.x;
  const int wv = t >> 6, lane = t & 63;
  const int grp = lane >> 3, c8 = lane & 7;
  __shared__ float lw[64][64];
  __shared__ float hbuf[8][64];
  for (int i = t; i < 4096; i += 512) lw[i >> 6][i & 63] = linW[i];

  const int node = blockIdx.x * 8 + wv;
  const bool active = node < n;
  const int cb = c8 * 8;
  const unsigned loff = (unsigned)c8 << 4;
  const char* xl8 = (const char*)xlb;

  f2 xr2[4];
  int r0 = 0, r1 = 0;
  if (active) {
    uint4 p = *(const uint4*)((const char*)xrb + (((unsigned)node << 7) + loff));
    xr2[0] = bfpair(p.x); xr2[1] = bfpair(p.y); xr2[2] = bfpair(p.z); xr2[3] = bfpair(p.w);
    r0 = rowptr[node];
    r1 = rowptr[node + 1];
  } else {
#pragma unroll
    for (int j = 0; j < 4; ++j) xr2[j] = (f2){0.f, 0.f};
  }
  f2 at2[4];
  {
    float4 a0 = *(const float4*)(att + cb);
    float4 a1 = *(const float4*)(att + cb + 4);
    at2[0] = (f2){a0.x * L2E, a0.y * L2E}; at2[1] = (f2){a0.z * L2E, a0.w * L2E};
    at2[2] = (f2){a1.x * L2E, a1.y * L2E}; at2[3] = (f2){a1.z * L2E, a1.w * L2E};
  }

  float s = 0.f;
  f2 o2[4];
#pragma unroll
  for (int j = 0; j < 4; ++j) o2[j] = (f2){0.f, 0.f};

  uint4 vpk = {0u, 0u, 0u, 0u};
  {
    int i0 = r0 + grp;
    if (i0 < r1) vpk = *(const uint4*)(xl8 + ((((unsigned)csr_src[i0]) << 7) + loff));
  }
  bool valid = (r0 + grp) < r1;

  for (int base = r0; base < r1; base += 8) {
    const uint4 pc = vpk;
    const bool vld = valid;
    int inext = base + 8 + grp;
    valid = inext < r1;
    if (valid) vpk = *(const uint4*)(xl8 + ((((unsigned)csr_src[inext]) << 7) + loff));

    f2 v0 = bfpair(pc.x), v1 = bfpair(pc.y), v2 = bfpair(pc.z), v3 = bfpair(pc.w);
    f2 e0 = v0 + xr2[0]; e0 = __builtin_elementwise_max(e0, e0 * LRELU_SLOPE);
    f2 e1 = v1 + xr2[1]; e1 = __builtin_elementwise_max(e1, e1 * LRELU_SLOPE);
    f2 e2 = v2 + xr2[2]; e2 = __builtin_elementwise_max(e2, e2 * LRELU_SLOPE);
    f2 e3 = v3 + xr2[3]; e3 = __builtin_elementwise_max(e3, e3 * LRELU_SLOPE);
    f2 sc2 = e0 * at2[0];
    sc2 += e1 * at2[1];
    sc2 += e2 * at2[2];
    sc2 += e3 * at2[3];
    float sc = sc2.x + sc2.y;
    sc = dpp_add<0xB1>(sc);
    sc = dpp_add<0x4E>(sc);
    sc += __shfl_xor(sc, 4);
    if (!vld) sc = -INFINITY;
    const float w = fast_exp2(sc);
    s += w;
    o2[0] += v0 * w;
    o2[1] += v1 * w;
    o2[2] += v2 * w;
    o2[3] += v3 * w;
  }

  float o[8] = {o2[0].x, o2[0].y, o2[1].x, o2[1].y, o2[2].x, o2[2].y, o2[3].x, o2[3].y};
#pragma unroll
  for (int off = 8; off < 64; off <<= 1) {
#pragma unroll
    for (int i = 0; i < 8; ++i) o[i] += __shfl_xor(o[i], off);
    s += __shfl_xor(s, off);
  }

  const float inv = 1.f / (s + 1e-16f);
  float val[8];
  {
    float4 b0 = *(const float4*)(bo + cb);
    float4 b1 = *(const float4*)(bo + cb + 4);
    val[0] = fmaf(o[0], inv, b0.x); val[1] = fmaf(o[1], inv, b0.y);
    val[2] = fmaf(o[2], inv, b0.z); val[3] = fmaf(o[3], inv, b0.w);
    val[4] = fmaf(o[4], inv, b1.x); val[5] = fmaf(o[5], inv, b1.y);
    val[6] = fmaf(o[6], inv, b1.z); val[7] = fmaf(o[7], inv, b1.w);
  }

  float ls = 0.f;
#pragma unroll
  for (int i = 0; i < 8; ++i) ls += val[i];
  ls = dpp_add<0xB1>(ls);
  ls = dpp_add<0x4E>(ls);
  ls += __shfl_xor(ls, 4);
  float mu = ls * (1.f / 64.f);
  float d[8], q = 0.f;
#pragma unroll
  for (int i = 0; i < 8; ++i) { d[i] = val[i] - mu; q = fmaf(d[i], d[i], q); }
  q = dpp_add<0xB1>(q);
  q = dpp_add<0x4E>(q);
  q += __shfl_xor(q, 4);
  float var = q * (1.f / 64.f);
  const float rs = rsqrtf(var + 1e-5f);

  if (grp == 0) {
    float4 g0 = *(const float4*)(gam + cb);
    float4 g1 = *(const float4*)(gam + cb + 4);
    float4 e0 = *(const float4*)(bet + cb);
    float4 e1 = *(const float4*)(bet + cb + 4);
    float* hb = &hbuf[wv][cb];
    hb[0] = fmaf(d[0] * rs, g0.x, e0.x); hb[1] = fmaf(d[1] * rs, g0.y, e0.y);
    hb[2] = fmaf(d[2] * rs, g0.z, e0.z); hb[3] = fmaf(d[3] * rs, g0.w, e0.w);
    hb[4] = fmaf(d[4] * rs, g1.x, e1.x); hb[5] = fmaf(d[5] * rs, g1.y, e1.y);
    hb[6] = fmaf(d[6] * rs, g1.z, e1.z); hb[7] = fmaf(d[7] * rs, g1.w, e1.w);
  }
  __syncthreads();

  float acc = linb[lane];
#pragma unroll 8
  for (int k = 0; k < 64; ++k) acc = fmaf(hbuf[wv][k], lw[k][lane], acc);
  if (active) outp[(size_t)node * 64 + lane] = acc;
}

extern "C" void kernel_launch(void* const* d_in, const int* in_sizes, int n_in,
                              void* d_out, int out_size, void* d_ws, size_t ws_size,
                              hipStream_t stream) {
  const float* x    = (const float*)d_in[0];
  const int*   eidx = (const int*)d_in[1];
  const int Nn = in_sizes[0] / 128;
  const int Ee = in_sizes[1] / 2;
  const int* src = eidx;
  const int* dst = eidx + Ee;

  const float* W1l = (const float*)d_in[3];  const float* b1l = (const float*)d_in[4];
  const float* W1r = (const float*)d_in[5];  const float* b1r = (const float*)d_in[6];
  const float* a1  = (const float*)d_in[7];  const float* bo1 = (const float*)d_in[8];
  const float* g1  = (const float*)d_in[9];  const float* be1 = (const float*)d_in[10];
  const float* W2l = (const float*)d_in[11]; const float* b2l = (const float*)d_in[12];
  const float* W2r = (const float*)d_in[13]; const float* b2r = (const float*)d_in[14];
  const float* a2  = (const float*)d_in[15]; const float* bo2 = (const float*)d_in[16];
  const float* g2  = (const float*)d_in[17]; const float* be2 = (const float*)d_in[18];
  const float* W3l = (const float*)d_in[19]; const float* b3l = (const float*)d_in[20];
  const float* W3r = (const float*)d_in[21]; const float* b3r = (const float*)d_in[22];
  const float* a3  = (const float*)d_in[23]; const float* bo3 = (const float*)d_in[24];
  const float* g3  = (const float*)d_in[25]; const float* be3 = (const float*)d_in[26];
  const float* linW = (const float*)d_in[27]; const float* linb = (const float*)d_in[28];

  char* ws = (char*)d_ws;
  unsigned short* xl   = (unsigned short*)ws; ws += (size_t)Nn * 256 * 2;
  unsigned short* xr   = (unsigned short*)ws; ws += (size_t)Nn * 256 * 2;
  unsigned short* Xb   = (unsigned short*)ws; ws += (size_t)Nn * 256 * 2;
  unsigned short* Wt1l = (unsigned short*)ws; ws += 256 * 128 * 2;
  unsigned short* Wt1r = (unsigned short*)ws; ws += 256 * 128 * 2;
  unsigned short* Wt2l = (unsigned short*)ws; ws += 256 * 256 * 2;
  unsigned short* Wt2r = (unsigned short*)ws; ws += 256 * 256 * 2;
  unsigned short* Wt3l = (unsigned short*)ws; ws += 64 * 256 * 2;
  unsigned short* Wt3r = (unsigned short*)ws; ws += 64 * 256 * 2;
  int*   deg    = (int*)ws;    ws += (size_t)Nn * 4;
  int*   rowptr = (int*)ws;    ws += (size_t)(Nn + 1) * 4;
  int*   bsum   = (int*)ws;    ws += 1024 * 4;
  int*   boff   = (int*)ws;    ws += 1024 * 4;
  int*   csr_src= (int*)ws;    ws += (size_t)(Ee + 16) * 4;

  const int eblk = (Ee + 255) / 256;
  const int nblk = (Nn + 255) / 256;

  // ---------------- CSR build (by dst) + all weight conversions ----------------
  hipMemsetAsync(deg, 0, (size_t)Nn * 4, stream);
  hist_deg<<<eblk, 256, 0, stream>>>(dst, deg, Ee);
  wt_cvt_all<<<dim3(32, 6), 256, 0, stream>>>(W1l, W1r, W2l, W2r, W3l, W3r,
                                              Wt1l, Wt1r, Wt2l, Wt2r, Wt3l, Wt3r);
  scan_blk<<<nblk, 256, 0, stream>>>(deg, rowptr, bsum, Nn);
  scan_top<<<1, 1024, 0, stream>>>(bsum, boff, rowptr, nblk, Nn);
  scan_add<<<nblk, 256, 0, stream>>>(rowptr, boff, Nn);
  fill_csr<<<(Ee + 16 + 255) / 256, 256, 0, stream>>>(src, dst, rowptr, deg, csr_src, Ee);

  const int gdblk = (Nn + 63) / 64;

  // ---------------- layer 1: 128 -> 4x64 (fused f32->bf16 staging) ----------------
  gemm_side<128, true><<<dim3(gdblk, 2), 256, 0, stream>>>(x, Wt1l, Wt1r, b1l, b1r, xl, xr, Nn);
  gat_fused4<<<(Nn + 3) / 4, 256, 0, stream>>>(xl, xr, a1, rowptr, csr_src, bo1, g1, be1, Xb, Nn);

  // ---------------- layer 2: 256 -> 4x64 ----------------
  gemm_side<256, false><<<dim3(gdblk, 2), 256, 0, stream>>>(Xb, Wt2l, Wt2r, b2l, b2r, xl, xr, Nn);
  gat_fused4<<<(Nn + 3) / 4, 256, 0, stream>>>(xl, xr, a2, rowptr, csr_src, bo2, g2, be2, Xb, Nn);

  // ---------------- layer 3: 256 -> 1x64 + LN + final linear ----------------
  gemm_n64<256><<<dim3(gdblk, 2), 256, 0, stream>>>(Xb, Wt3l, Wt3r, b3l, b3r, xl, xr, Nn);
  gat1_lin<<<(Nn + 7) / 8, 512, 0, stream>>>(xl, xr, a3, rowptr, csr_src, bo3, g3, be3,
                                             linW, linb, (float*)d_out, Nn);
}